// Round 7
// baseline (146.000 us; speedup 1.0000x reference)
//
#include <hip/hip_runtime.h>
#include <hip/hip_bf16.h>

#define T_TOK 512
#define H_DIM 2048
#define E_NUM 8
#define I_DIM 1024

typedef __attribute__((ext_vector_type(8))) short short8;
typedef __attribute__((ext_vector_type(4))) float f32x4;

// round-to-nearest-even float -> bf16 (as ushort)
__device__ __forceinline__ unsigned short f2bf(float f) {
    unsigned int u = __float_as_uint(f);
    u += 0x7fff + ((u >> 16) & 1);
    return (unsigned short)(u >> 16);
}

// 8 fp32 -> short8 of bf16 via packed cvt (RNE)
__device__ __forceinline__ short8 cvt8(float4 a, float4 b) {
    union { short8 s; __hip_bfloat162 h[4]; } u;
    u.h[0] = __float22bfloat162_rn(make_float2(a.x, a.y));
    u.h[1] = __float22bfloat162_rn(make_float2(a.z, a.w));
    u.h[2] = __float22bfloat162_rn(make_float2(b.x, b.y));
    u.h[3] = __float22bfloat162_rn(make_float2(b.z, b.w));
    return u.s;
}

// ---------------------------------------------------------------
// Kernel 0: x -> bf16 (1M elems, 8/thread)
// ---------------------------------------------------------------
__global__ __launch_bounds__(256) void xcvt_kernel(
    const float* __restrict__ x, unsigned short* __restrict__ xb)
{
    int i = (blockIdx.x * 256 + threadIdx.x) * 8;
    float4 v0 = *(const float4*)(x + i);
    float4 v1 = *(const float4*)(x + i + 4);
    *(short8*)(xb + i) = cvt8(v0, v1);
}

// ---------------------------------------------------------------
// Kernel 1: routing. 1 block, 512 threads.
// ---------------------------------------------------------------
__global__ __launch_bounds__(512) void routing_kernel(
    const float* __restrict__ logits,
    int* __restrict__ count, int* __restrict__ bucket,
    float* __restrict__ pair_w)
{
    int t = threadIdx.x;
    if (t < E_NUM) count[t] = 0;
    __syncthreads();

    float p[E_NUM];
    float m = -INFINITY;
#pragma unroll
    for (int e = 0; e < E_NUM; ++e) {
        p[e] = logits[t * E_NUM + e];
        m = fmaxf(m, p[e]);
    }
#pragma unroll
    for (int e = 0; e < E_NUM; ++e) p[e] = expf(p[e] - m);
    int i0 = 0;
#pragma unroll
    for (int e = 1; e < E_NUM; ++e) if (p[e] > p[i0]) i0 = e;
    int i1 = (i0 == 0) ? 1 : 0;
#pragma unroll
    for (int e = 0; e < E_NUM; ++e) if (e != i0 && p[e] > p[i1]) i1 = e;
    float denom = p[i0] + p[i1];
    pair_w[2 * t + 0] = p[i0] / denom;
    pair_w[2 * t + 1] = p[i1] / denom;

    int pos0 = atomicAdd(&count[i0], 1);
    bucket[i0 * T_TOK + pos0] = 2 * t + 0;
    int pos1 = atomicAdd(&count[i1], 1);
    bucket[i1 * T_TOK + pos1] = 2 * t + 1;
}

// ---------------------------------------------------------------
// Kernel 2: grouped GEMM1 + SiLU. BM=128, BN=16 gate + 16 up, BK=256.
// REGISTER-STAGED staging (T14): global_load_dwordx4 (deep miss queues)
// -> cvt to bf16 -> XOR-swizzled ds_write_b128. Double-buffered bf16
// LDS (16 KB x 2), ONE __syncthreads per K-iter. A-fragments read
// directly from global xb (L2-resident, 2 MB). A-loads issued BEFORE
// staging loads (vmcnt retires in-order; don't queue L2 hits behind
// HBM misses).
// 4 waves; wave wid = rows [wid*32, wid*32+32), all 16 g + 16 u cols.
// ---------------------------------------------------------------
__global__ __launch_bounds__(256) void gemm1_silu_kernel(
    const unsigned short* __restrict__ xb, const float* __restrict__ w13,
    const int* __restrict__ count, const int* __restrict__ bucket,
    __hip_bfloat16* __restrict__ act)
{
    const int e   = blockIdx.z;
    const int n_e = count[e];
    const int m0  = blockIdx.y * 128;
    if (m0 >= n_e) return;
    const int n0  = blockIdx.x * 16;

    // bf16 tiles: 16 rows x 256 cols (512 B rows), double-buffered
    __shared__ unsigned short sG[2][16 * 256];
    __shared__ unsigned short sU[2][16 * 256];

    const int tid  = threadIdx.x;
    const int lane = tid & 63;
    const int wid  = tid >> 6;     // 0..3
    const int fr   = lane & 15;
    const int fq   = lane >> 4;

    // ---- staging geometry: wave stages G rows [4*wid,4*wid+4) + U same.
    // lane covers row 4*wid + (lane>>4), floats [(lane&15)*16, +16).
    const int srow = 4 * wid + (lane >> 4);        // tile row 0..15
    const int scol = (lane & 15) * 16;             // float offset in row-chunk
    const float* gsrc = w13 + ((size_t)e * 2048 + n0 + srow) * H_DIM + scol;
    const float* usrc = w13 + ((size_t)e * 2048 + I_DIM + n0 + srow) * H_DIM + scol;
    // write slots: granules 2*(lane&15)+w, XOR row swizzle
    const int wg0 = (2 * (lane & 15) + 0) ^ (srow & 7);
    const int wg1 = (2 * (lane & 15) + 1) ^ (srow & 7);

    // ---- A row pointers (2 m-frags per wave)
    const unsigned short* ar[2];
#pragma unroll
    for (int m = 0; m < 2; ++m) {
        int r   = m0 + wid * 32 + m * 16 + fr;
        int tok = bucket[e * T_TOK + min(r, n_e - 1)] >> 1;
        ar[m] = xb + (size_t)tok * H_DIM + fq * 8;
    }

    f32x4 accg[2] = {};
    f32x4 accu[2] = {};

    // ---- prologue: stage tile 0 into buf 0
    {
        float4 g0 = *(const float4*)(gsrc + 0),  g1 = *(const float4*)(gsrc + 4);
        float4 g2 = *(const float4*)(gsrc + 8),  g3 = *(const float4*)(gsrc + 12);
        float4 u0 = *(const float4*)(usrc + 0),  u1 = *(const float4*)(usrc + 4);
        float4 u2 = *(const float4*)(usrc + 8),  u3 = *(const float4*)(usrc + 12);
        *(short8*)&sG[0][srow * 256 + wg0 * 8] = cvt8(g0, g1);
        *(short8*)&sG[0][srow * 256 + wg1 * 8] = cvt8(g2, g3);
        *(short8*)&sU[0][srow * 256 + wg0 * 8] = cvt8(u0, u1);
        *(short8*)&sU[0][srow * 256 + wg1 * 8] = cvt8(u2, u3);
    }
    __syncthreads();

    for (int t = 0; t < 8; ++t) {                  // 8 K-tiles of 256
        const int kb      = t * 256;
        const int kb_next = min(t + 1, 7) * 256;   // clamped fake tail

        // (1) A-fragment loads for tile t (L2-fast, issue first)
        short8 a[8][2];
#pragma unroll
        for (int kk = 0; kk < 8; ++kk)
#pragma unroll
            for (int m = 0; m < 2; ++m)
                a[kk][m] = *(const short8*)(ar[m] + kb + kk * 32);

        // (2) staging loads for tile t+1 (HBM, in flight across compute)
        float4 g0 = *(const float4*)(gsrc + kb_next + 0);
        float4 g1 = *(const float4*)(gsrc + kb_next + 4);
        float4 g2 = *(const float4*)(gsrc + kb_next + 8);
        float4 g3 = *(const float4*)(gsrc + kb_next + 12);
        float4 u0 = *(const float4*)(usrc + kb_next + 0);
        float4 u1 = *(const float4*)(usrc + kb_next + 4);
        float4 u2 = *(const float4*)(usrc + kb_next + 8);
        float4 u3 = *(const float4*)(usrc + kb_next + 12);

        // (3) compute tile t from buf t&1
        const unsigned short* G = sG[t & 1];
        const unsigned short* U = sU[t & 1];
#pragma unroll
        for (int kk = 0; kk < 8; ++kk) {
            int slot = (kk * 4 + fq) ^ (fr & 7);
            short8 bg = *(const short8*)&G[fr * 256 + slot * 8];
            short8 bu = *(const short8*)&U[fr * 256 + slot * 8];
#pragma unroll
            for (int m = 0; m < 2; ++m) {
                accg[m] = __builtin_amdgcn_mfma_f32_16x16x32_bf16(a[kk][m], bg, accg[m], 0, 0, 0);
                accu[m] = __builtin_amdgcn_mfma_f32_16x16x32_bf16(a[kk][m], bu, accu[m], 0, 0, 0);
            }
        }

        // (4) cvt + write tile t+1 into buf (t+1)&1 (freed by prev barrier)
        unsigned short* Gw = (unsigned short*)sG[(t + 1) & 1];
        unsigned short* Uw = (unsigned short*)sU[(t + 1) & 1];
        *(short8*)&Gw[srow * 256 + wg0 * 8] = cvt8(g0, g1);
        *(short8*)&Gw[srow * 256 + wg1 * 8] = cvt8(g2, g3);
        *(short8*)&Uw[srow * 256 + wg0 * 8] = cvt8(u0, u1);
        *(short8*)&Uw[srow * 256 + wg1 * 8] = cvt8(u2, u3);

        // (5) one barrier: writes visible, reads of this buf complete
        __syncthreads();
    }

    // epilogue: silu(gate)*up -> act (bf16)
#pragma unroll
    for (int m = 0; m < 2; ++m) {
#pragma unroll
        for (int j = 0; j < 4; ++j) {
            int r = m0 + wid * 32 + m * 16 + fq * 4 + j;
            if (r < n_e) {
                int pid = bucket[e * T_TOK + r];
                float g = accg[m][j];
                float u = accu[m][j];
                float sg = g / (1.f + expf(-g));
                *(unsigned short*)(act + (size_t)pid * I_DIM + n0 + fr) = f2bf(sg * u);
            }
        }
    }
}

// ---------------------------------------------------------------
// Kernel 3: grouped GEMM2. BM=128, BN=16, BK=256, K=1024 (4 iters).
// Same register-staged pipeline. A = act bf16 (global, L2/L3-hot),
// B = w2 fp32 staged via regs -> bf16 LDS.
// ---------------------------------------------------------------
__global__ __launch_bounds__(256) void gemm2_kernel(
    const __hip_bfloat16* __restrict__ act, const float* __restrict__ w2,
    const int* __restrict__ count, const int* __restrict__ bucket,
    float* __restrict__ y)
{
    const int e   = blockIdx.z;
    const int n_e = count[e];
    const int m0  = blockIdx.y * 128;
    if (m0 >= n_e) return;
    const int h0  = blockIdx.x * 16;

    __shared__ unsigned short sB[2][16 * 256];

    const int tid  = threadIdx.x;
    const int lane = tid & 63;
    const int wid  = tid >> 6;
    const int fr   = lane & 15;
    const int fq   = lane >> 4;

    const int srow = 4 * wid + (lane >> 4);
    const int scol = (lane & 15) * 16;
    const float* bsrc = w2 + ((size_t)e * H_DIM + h0 + srow) * I_DIM + scol;
    const int wg0 = (2 * (lane & 15) + 0) ^ (srow & 7);
    const int wg1 = (2 * (lane & 15) + 1) ^ (srow & 7);

    const unsigned short* ar[2];
#pragma unroll
    for (int m = 0; m < 2; ++m) {
        int r   = m0 + wid * 32 + m * 16 + fr;
        int pid = bucket[e * T_TOK + min(r, n_e - 1)];
        ar[m] = (const unsigned short*)act + (size_t)pid * I_DIM + fq * 8;
    }

    f32x4 acc[2] = {};

    {
        float4 b0 = *(const float4*)(bsrc + 0),  b1 = *(const float4*)(bsrc + 4);
        float4 b2 = *(const float4*)(bsrc + 8),  b3 = *(const float4*)(bsrc + 12);
        *(short8*)&sB[0][srow * 256 + wg0 * 8] = cvt8(b0, b1);
        *(short8*)&sB[0][srow * 256 + wg1 * 8] = cvt8(b2, b3);
    }
    __syncthreads();

    for (int t = 0; t < 4; ++t) {                  // 4 K-tiles of 256
        const int kb      = t * 256;
        const int kb_next = min(t + 1, 3) * 256;

        short8 a[8][2];
#pragma unroll
        for (int kk = 0; kk < 8; ++kk)
#pragma unroll
            for (int m = 0; m < 2; ++m)
                a[kk][m] = *(const short8*)(ar[m] + kb + kk * 32);

        float4 b0 = *(const float4*)(bsrc + kb_next + 0);
        float4 b1 = *(const float4*)(bsrc + kb_next + 4);
        float4 b2 = *(const float4*)(bsrc + kb_next + 8);
        float4 b3 = *(const float4*)(bsrc + kb_next + 12);

        const unsigned short* B = sB[t & 1];
#pragma unroll
        for (int kk = 0; kk < 8; ++kk) {
            int slot = (kk * 4 + fq) ^ (fr & 7);
            short8 bb = *(const short8*)&B[fr * 256 + slot * 8];
#pragma unroll
            for (int m = 0; m < 2; ++m)
                acc[m] = __builtin_amdgcn_mfma_f32_16x16x32_bf16(a[kk][m], bb, acc[m], 0, 0, 0);
        }

        unsigned short* Bw = (unsigned short*)sB[(t + 1) & 1];
        *(short8*)&Bw[srow * 256 + wg0 * 8] = cvt8(b0, b1);
        *(short8*)&Bw[srow * 256 + wg1 * 8] = cvt8(b2, b3);

        __syncthreads();
    }

#pragma unroll
    for (int m = 0; m < 2; ++m) {
#pragma unroll
        for (int j = 0; j < 4; ++j) {
            int r = m0 + wid * 32 + m * 16 + fq * 4 + j;
            if (r < n_e) {
                int pid = bucket[e * T_TOK + r];
                y[(size_t)pid * H_DIM + h0 + fr] = acc[m][j];
            }
        }
    }
}

// ---------------------------------------------------------------
// Kernel 4: combine. out[t,h] = w0*y[2t,h] + w1*y[2t+1,h]
// ---------------------------------------------------------------
__global__ __launch_bounds__(256) void combine_kernel(
    const float* __restrict__ y, const float* __restrict__ pair_w,
    float* __restrict__ out)
{
    int idx = blockIdx.x * 256 + threadIdx.x;
    int t = idx >> 9;
    int c = idx & 511;
    float w0 = pair_w[2 * t + 0];
    float w1 = pair_w[2 * t + 1];
    float4 y0 = ((const float4*)(y + (size_t)(2 * t + 0) * H_DIM))[c];
    float4 y1 = ((const float4*)(y + (size_t)(2 * t + 1) * H_DIM))[c];
    float4 o;
    o.x = w0 * y0.x + w1 * y1.x;
    o.y = w0 * y0.y + w1 * y1.y;
    o.z = w0 * y0.z + w1 * y1.z;
    o.w = w0 * y0.w + w1 * y1.w;
    ((float4*)(out + (size_t)t * H_DIM))[c] = o;
}

extern "C" void kernel_launch(void* const* d_in, const int* in_sizes, int n_in,
                              void* d_out, int out_size, void* d_ws, size_t ws_size,
                              hipStream_t stream) {
    const float* x      = (const float*)d_in[0];
    const float* logits = (const float*)d_in[1];
    const float* w13    = (const float*)d_in[2];
    const float* w2     = (const float*)d_in[3];
    float* out = (float*)d_out;

    // workspace layout (16B-aligned sections)
    int*   count  = (int*)d_ws;                                        // 8
    int*   bucket = count + E_NUM;                                     // 4096
    float* pair_w = (float*)(bucket + E_NUM * T_TOK);                  // 1024
    unsigned short* xb = (unsigned short*)(pair_w + 2 * T_TOK);        // 512*2048 bf16 (2 MB)
    __hip_bfloat16* act = (__hip_bfloat16*)(xb + (size_t)T_TOK * H_DIM);   // 1024*1024 bf16 (2 MB)
    float* ybuf   = (float*)((unsigned short*)act + (size_t)2 * T_TOK * I_DIM); // 1024*2048 f32 (8 MB)

    xcvt_kernel<<<(T_TOK * H_DIM / 8) / 256, 256, 0, stream>>>(x, xb);
    routing_kernel<<<1, 512, 0, stream>>>(logits, count, bucket, pair_w);
    gemm1_silu_kernel<<<dim3(I_DIM / 16, 4, E_NUM), 256, 0, stream>>>(
        xb, w13, count, bucket, act);
    gemm2_kernel<<<dim3(H_DIM / 16, 4, E_NUM), 256, 0, stream>>>(
        act, w2, count, bucket, ybuf);
    combine_kernel<<<(T_TOK * (H_DIM / 4)) / 256, 256, 0, stream>>>(
        ybuf, pair_w, out);
}